// Round 14
// baseline (93.767 us; speedup 1.0000x reference)
//
#include <hip/hip_runtime.h>
#include <hip/hip_bf16.h>
#include <cstdint>
#include <cstddef>

#define EPS 1e-5f
#define NEG 0.2f

static constexpr int B_ = 8, N_ = 4096, K_ = 20, M_ = B_ * N_;  // M = 32768

typedef __attribute__((ext_vector_type(8))) _Float16 f16x8;
typedef __attribute__((ext_vector_type(4))) float f32x4;

#define VMCNT(n) asm volatile("s_waitcnt vmcnt(" #n ")" ::: "memory")

// async global->LDS, 16B per lane; LDS dest = wave-uniform base + lane*16
__device__ __forceinline__ void gload_lds16(const _Float16* g, _Float16* l) {
  __builtin_amdgcn_global_load_lds(
      (const __attribute__((address_space(1))) uint32_t*)g,
      (__attribute__((address_space(3))) uint32_t*)l, 16, 0, 0);
}

// ---------------- prep + layer-1 C=3 GEMM, one kernel ------------------------
// blocks 0..511: gemm_c3 ; 512..1327: weight fold ; 1328: BN param table
__global__ __launch_bounds__(256) void prep_c3(
    const float* __restrict__ x, const float* __restrict__ w1,
    const float* __restrict__ w2, const float* __restrict__ w3,
    const float* __restrict__ w4, const float* __restrict__ w5,
    const float* __restrict__ w6,
    const float* __restrict__ g1, const float* __restrict__ b1, const float* __restrict__ m1, const float* __restrict__ v1,
    const float* __restrict__ g2, const float* __restrict__ b2, const float* __restrict__ m2, const float* __restrict__ v2,
    const float* __restrict__ g3, const float* __restrict__ b3, const float* __restrict__ m3, const float* __restrict__ v3,
    const float* __restrict__ g4, const float* __restrict__ b4, const float* __restrict__ m4, const float* __restrict__ v4,
    const float* __restrict__ g5, const float* __restrict__ b5, const float* __restrict__ m5, const float* __restrict__ v5,
    const float* __restrict__ g6, const float* __restrict__ b6, const float* __restrict__ m6, const float* __restrict__ v6,
    float* __restrict__ P, _Float16* __restrict__ Wh, _Float16* __restrict__ z) {
  const int bid = blockIdx.x, tid = threadIdx.x;
  if (bid < 512) {
    const int o  = tid & 63;
    const int pi = tid >> 6;
    const float ww0 = w1[o * 3 + 0], ww1 = w1[o * 3 + 1], ww2 = w1[o * 3 + 2];
    const float iv = g1[o] * rsqrtf(v1[o] + EPS);
    const int pbase = bid * 64;
    const int b = pbase >> 12;
    const int nbase = pbase & (N_ - 1);
    const float* xb = x + (size_t)b * 3 * N_;
    for (int pj = pi; pj < 64; pj += 4) {
      const int n = nbase + pj;
      const float x0 = xb[n], x1v = xb[N_ + n], x2v = xb[2 * N_ + n];
      z[(size_t)(pbase + pj) * 64 + o] = (_Float16)((x0 * ww0 + x1v * ww1 + x2v * ww2) * iv);
    }
    return;
  }
  if (bid == 1328) {
    const float* G[6]  = {g1, g2, g3, g4, g5, g6};
    const float* Bb[6] = {b1, b2, b3, b4, b5, b6};
    const float* Mm[6] = {m1, m2, m3, m4, m5, m6};
    const float* Vv[6] = {v1, v2, v3, v4, v5, v6};
    const int Cs[6] = {64, 64, 128, 256, 256, 128};
    const int OI[6] = {0, 128, 256, 512, 1024, 1536};
    const int OB[6] = {64, 192, 384, 768, 1280, 1664};
    for (int l = 0; l < 6; ++l) {
      for (int c = tid; c < Cs[l]; c += 256) {
        float iv = G[l][c] * rsqrtf(Vv[l][c] + EPS);
        P[OI[l] + c] = iv;
        P[OB[l] + c] = Bb[l][c] - Mm[l][c] * iv;
      }
    }
    return;
  }
  const int fb = bid - 512;
  const float* w; const float* g; const float* v; _Float16* dst; int lc, base;
  if (fb < 16)       { w = w2; g = g2; v = v2; dst = Wh + 0;      lc = 6; base = 0;   }
  else if (fb < 48)  { w = w3; g = g3; v = v3; dst = Wh + 4096;   lc = 6; base = 16;  }
  else if (fb < 176) { w = w4; g = g4; v = v4; dst = Wh + 12288;  lc = 7; base = 48;  }
  else if (fb < 688) { w = w5; g = g5; v = v5; dst = Wh + 45056;  lc = 9; base = 176; }
  else               { w = w6; g = g6; v = v6; dst = Wh + 176128; lc = 8; base = 688; }
  const int e = (fb - base) * 256 + tid;
  const int o = e >> lc;
  dst[e] = (_Float16)(w[e] * (g[o] * rsqrtf(v[o] + EPS)));
}

// ---------------- fused edge(C=64) + small GEMM (L1+L2g, L2+L3g) -------------
template <int BO>
__global__ __launch_bounds__(256) void edge_gemm64(
    const _Float16* __restrict__ z, const int* __restrict__ idx,
    const float* __restrict__ betap,
    const _Float16* __restrict__ W,           // (BO, 64) inv-folded
    _Float16* __restrict__ hout,              // h512 column base (ld 512)
    _Float16* __restrict__ zout, int ldzout) {
  constexpr int GW = BO / 8;
  constexpr int OJ = BO / 32;
  __shared__ _Float16 Asmem[128 * 64];
  __shared__ _Float16 Wsmem[BO * 64];

  const int tid = threadIdx.x, lane = tid & 63, wid = tid >> 6;
  const int batch = blockIdx.x & 7, chunk = blockIdx.x >> 3;
  const int bm0 = (batch << 12) + chunk * 128;
  const int lr = lane & 15, lk = lane >> 4;

  const _Float16* Wbase = W + (size_t)lr * 64 + lk * 8;
#pragma unroll
  for (int g = wid; g < GW; g += 4) {
    const int o = g >> 1, s = g & 1;
    gload_lds16(Wbase + (size_t)16 * o * 64 + s * 32, Wsmem + g * 512);
  }

  const int lid = tid & 7, cb = lid * 8;
  float bt[8];
#pragma unroll
  for (int q = 0; q < 8; ++q) bt[q] = betap[cb + q];
  const _Float16* zb = z + ((size_t)(batch << 12)) * 64;
#pragma unroll
  for (int pass = 0; pass < 4; ++pass) {
    const int pi = pass * 32 + (tid >> 3);
    const int p = bm0 + pi;
    const int* ip = idx + (size_t)p * K_;
    const int ir0 = ip[lid];
    const int ir1 = ip[8 + lid];
    const int ir2 = ip[16 + (lid & 3)];
    f16x8 mx = *reinterpret_cast<const f16x8*>(zb + (size_t)__shfl(ir0, 0, 8) * 64 + cb);
#pragma unroll
    for (int k = 1; k < K_; ++k) {
      const int g = (k < 8) ? __shfl(ir0, k, 8)
                  : (k < 16) ? __shfl(ir1, k - 8, 8)
                             : __shfl(ir2, k - 16, 8);
      const f16x8 v = *reinterpret_cast<const f16x8*>(zb + (size_t)g * 64 + cb);
#pragma unroll
      for (int q = 0; q < 8; ++q) mx[q] = v[q] > mx[q] ? v[q] : mx[q];
    }
    const f16x8 vc = *reinterpret_cast<const f16x8*>(z + (size_t)p * 64 + cb);
    f16x8 vo;
#pragma unroll
    for (int q = 0; q < 8; ++q) {
      const float e = (float)mx[q] - (float)vc[q] + bt[q];
      vo[q] = (_Float16)fmaxf(e, NEG * e);
    }
    *reinterpret_cast<f16x8*>(hout + (size_t)p * 512 + cb) = vo;
    const int i = pi >> 4, rr = pi & 15, s = cb >> 5, kk = (cb >> 3) & 3;
    *reinterpret_cast<f16x8*>(Asmem + (i * 2 + s) * 512 + ((kk << 4) | rr) * 8) = vo;
  }
  __syncthreads();

  const int wr = wid >> 1, wc = wid & 1;
  f32x4 acc[4][OJ];
#pragma unroll
  for (int i = 0; i < 4; ++i)
#pragma unroll
    for (int j = 0; j < OJ; ++j) acc[i][j] = (f32x4){0.f, 0.f, 0.f, 0.f};
#pragma unroll
  for (int s = 0; s < 2; ++s) {
    f16x8 av[4], wv[OJ];
#pragma unroll
    for (int i = 0; i < 4; ++i)
      av[i] = *reinterpret_cast<const f16x8*>(Asmem + ((wr * 4 + i) * 2 + s) * 512 + lane * 8);
#pragma unroll
    for (int j = 0; j < OJ; ++j)
      wv[j] = *reinterpret_cast<const f16x8*>(Wsmem + ((wc * OJ + j) * 2 + s) * 512 + lane * 8);
#pragma unroll
    for (int i = 0; i < 4; ++i)
#pragma unroll
      for (int j = 0; j < OJ; ++j)
        acc[i][j] = __builtin_amdgcn_mfma_f32_16x16x32_f16(av[i], wv[j], acc[i][j], 0, 0, 0);
  }

#pragma unroll
  for (int j = 0; j < OJ; ++j) {
    const int o = wc * (BO / 2) + 16 * j + lr;
#pragma unroll
    for (int i = 0; i < 4; ++i) {
      const int r0 = bm0 + wr * 64 + 16 * i + lk * 4;
#pragma unroll
      for (int q = 0; q < 4; ++q)
        zout[(size_t)(r0 + q) * ldzout + o] = (_Float16)acc[i][j][q];
    }
  }
}

// ---------------- L4: edge(C=128) in regs + 8-wave GEMM (128x256, C=128) -----
__global__ __launch_bounds__(512, 1) void edge_gemm_l4(
    const _Float16* __restrict__ z3,          // (M,128)
    const int* __restrict__ idx,
    const float* __restrict__ btE,            // edge beta (128)
    const _Float16* __restrict__ W4,          // (256,128)
    _Float16* __restrict__ h512,              // x3 -> cols 128..255
    _Float16* __restrict__ z4out) {           // (M,256)
  constexpr int SB = 24 * 512;                // 8 A-groups + 16 W-groups per K-step
  __shared__ _Float16 lds[4 * SB];            // 96 KB

  const int tid = threadIdx.x, lane = tid & 63, wid = tid >> 6;
  const int wr = wid >> 2, wc = wid & 3;
  const int bid = blockIdx.x, batch = bid & 7;
  const int bm0 = (batch << 12) + (bid >> 3) * 128;
  const int lr = lane & 15, lk = lane >> 4;

  // upfront W4 staging: 64 groups (ob 0..15, kk 0..3), 8 per wave
  const _Float16* Wb = W4 + (size_t)lr * 128 + lk * 8;
#pragma unroll
  for (int q = 0; q < 8; ++q) {
    const int gg = wid * 8 + q;
    const int ob = gg >> 2, kk = gg & 3;
    gload_lds16(Wb + (size_t)16 * ob * 128 + kk * 32, &lds[kk * SB + (8 + ob) * 512]);
  }

  // edge phase: TPP=16, 32 points/pass, 4 passes
  const int lid = tid & 15, cb = lid * 8;
  float bt[8];
#pragma unroll
  for (int q = 0; q < 8; ++q) bt[q] = btE[cb + q];
  const _Float16* zb = z3 + ((size_t)(batch << 12)) * 128;
  f16x8 x3r[4];
#pragma unroll
  for (int pass = 0; pass < 4; ++pass) {
    const int pi = pass * 32 + (tid >> 4);
    const int p = bm0 + pi;
    const int* ip = idx + (size_t)p * K_;
    const int ir0 = ip[lid];
    const int ir1 = (lid < 4) ? ip[16 + lid] : 0;
    f16x8 mx = *reinterpret_cast<const f16x8*>(zb + (size_t)__shfl(ir0, 0, 16) * 128 + cb);
#pragma unroll
    for (int k = 1; k < K_; ++k) {
      const int g = (k < 16) ? __shfl(ir0, k, 16) : __shfl(ir1, k - 16, 16);
      const f16x8 v = *reinterpret_cast<const f16x8*>(zb + (size_t)g * 128 + cb);
#pragma unroll
      for (int q = 0; q < 8; ++q) mx[q] = v[q] > mx[q] ? v[q] : mx[q];
    }
    const f16x8 vc = *reinterpret_cast<const f16x8*>(z3 + (size_t)p * 128 + cb);
    f16x8 vo;
#pragma unroll
    for (int q = 0; q < 8; ++q) {
      const float e = (float)mx[q] - (float)vc[q] + bt[q];
      vo[q] = (_Float16)fmaxf(e, NEG * e);
    }
    x3r[pass] = vo;
    *reinterpret_cast<f16x8*>(h512 + (size_t)p * 512 + 128 + cb) = vo;
  }
  // ds_write A fragments for all 4 K-step buffers
  {
    const int kk = (cb >> 3) & 3;
    const int ts = cb >> 5;                 // K-step 0..3
    const int rr = (tid >> 4) & 15;
#pragma unroll
    for (int pp = 0; pp < 4; ++pp) {
      const int grp = pp * 2 + (tid >> 8);
      *reinterpret_cast<f16x8*>(&lds[ts * SB + grp * 512 + ((kk << 4) | rr) * 8]) = x3r[pp];
    }
  }
  __syncthreads();   // drains vmcnt (W) + lgkmcnt (A writes)

  // GEMM: NK=4, all resident, no further barriers
  f32x4 acc[4][4];
#pragma unroll
  for (int i = 0; i < 4; ++i)
#pragma unroll
    for (int j = 0; j < 4; ++j) acc[i][j] = (f32x4){0.f, 0.f, 0.f, 0.f};
#pragma unroll
  for (int t = 0; t < 4; ++t) {
    f16x8 av[4], wv[4];
#pragma unroll
    for (int i = 0; i < 4; ++i)
      av[i] = *reinterpret_cast<const f16x8*>(&lds[t * SB + (wr * 4 + i) * 512 + lane * 8]);
#pragma unroll
    for (int j = 0; j < 4; ++j)
      wv[j] = *reinterpret_cast<const f16x8*>(&lds[t * SB + (8 + wc * 4 + j) * 512 + lane * 8]);
#pragma unroll
    for (int i = 0; i < 4; ++i)
#pragma unroll
      for (int j = 0; j < 4; ++j)
        acc[i][j] = __builtin_amdgcn_mfma_f32_16x16x32_f16(av[i], wv[j], acc[i][j], 0, 0, 0);
  }

#pragma unroll
  for (int j = 0; j < 4; ++j) {
    const int o = wc * 64 + 16 * j + lr;
#pragma unroll
    for (int i = 0; i < 4; ++i) {
      const int r0 = bm0 + wr * 64 + 16 * i + lk * 4;
#pragma unroll
      for (int q = 0; q < 4; ++q)
        z4out[(size_t)(r0 + q) * 256 + o] = (_Float16)acc[i][j][q];
    }
  }
}

// ---------------- e4 + L5 + L6 + L7 fused, 8-wave ----------------------------
// Phase 0: stage(0,1) issued; e4 edge (gathers from z4, L2-resident) scattered
//          directly into H5 LDS in A-fragment layout (x4 never goes global).
// Phase A: L5 ring-4 GEMM, NK=16; t<8 A from h512 ring-staged, t>=8 A from H5.
// Phase B: h5 -> H5 (after barrier), W6 -> ring; L6 GEMM + fused L7 dot.
__global__ __launch_bounds__(512, 1) void gemm_e4l567(
    const _Float16* __restrict__ A,           // h512, ld 512 (cols 0..255 used)
    const _Float16* __restrict__ z4,          // (M,256)
    const int* __restrict__ idx,
    const float* __restrict__ bt4,            // edge beta (256)
    const _Float16* __restrict__ W5,          // (256,512)
    const float* __restrict__ bt5,
    const _Float16* __restrict__ W6,          // (128,256)
    const float* __restrict__ bt6,
    const float* __restrict__ w7,             // (128)
    float* __restrict__ dout) {               // (M)
  constexpr int SB = 24 * 512;                // halves per ring buffer (24KB)
  constexpr int H5 = 4 * SB;                  // x4/h5 frag region (64KB)
  __shared__ _Float16 lds[4 * SB + 32768];    // 96KB + 64KB = 160KB

  const int tid = threadIdx.x, lane = tid & 63, wid = tid >> 6;
  const int wr = wid >> 2, wc = wid & 3;
  const int bid = blockIdx.x, batch = bid & 7;
  const int bm0 = (batch << 12) + (bid >> 3) * 128;      // batch-XCD swizzle
  const int lr = lane & 15, lk = lane >> 4;

  const _Float16* Abase = A + (size_t)(bm0 + lr) * 512 + lk * 8;
  const _Float16* W5b = W5 + (size_t)lr * 512 + lk * 8;

  auto stage = [&](int buf, int t) {
    _Float16* dst = &lds[buf * SB];
    if (t < 8) {
#pragma unroll
      for (int q = 0; q < 3; ++q) {
        const int g = wid * 3 + q;
        const _Float16* src = (g < 8)
            ? Abase + (size_t)16 * g * 512 + t * 32
            : W5b + (size_t)16 * (g - 8) * 512 + t * 32;
        gload_lds16(src, dst + g * 512);
      }
    } else {
#pragma unroll
      for (int q = 0; q < 2; ++q) {
        const int ob = wid * 2 + q;
        gload_lds16(W5b + (size_t)16 * ob * 512 + t * 32, dst + (8 + ob) * 512);
      }
    }
  };

  stage(0, 0);
  stage(1, 1);

  // ---- e4 edge phase: TPP=32, 16 points/pass, 8 passes; scatter to H5 ------
  {
    const int lid = tid & 31, cb = lid * 8;
    float bt[8];
#pragma unroll
    for (int q = 0; q < 8; ++q) bt[q] = bt4[cb + q];
    const _Float16* zb = z4 + ((size_t)(batch << 12)) * 256;
    const int ts8 = cb >> 5;                  // K-step - 8 (0..7)
    const int kk = (cb >> 3) & 3;
#pragma unroll
    for (int pass = 0; pass < 8; ++pass) {
      const int pi = pass * 16 + (tid >> 5);
      const int p = bm0 + pi;
      const int* ip = idx + (size_t)p * K_;
      const int ir = (lid < K_) ? ip[lid] : 0;
      f16x8 mx = *reinterpret_cast<const f16x8*>(zb + (size_t)__shfl(ir, 0, 32) * 256 + cb);
#pragma unroll
      for (int k = 1; k < K_; ++k) {
        const int g = __shfl(ir, k, 32);
        const f16x8 v = *reinterpret_cast<const f16x8*>(zb + (size_t)g * 256 + cb);
#pragma unroll
        for (int q = 0; q < 8; ++q) mx[q] = v[q] > mx[q] ? v[q] : mx[q];
      }
      const f16x8 vc = *reinterpret_cast<const f16x8*>(z4 + (size_t)p * 256 + cb);
      f16x8 vo;
#pragma unroll
      for (int q = 0; q < 8; ++q) {
        const float e = (float)mx[q] - (float)vc[q] + bt[q];
        vo[q] = (_Float16)fmaxf(e, NEG * e);
      }
      // A-fragment scatter: K-step 8+ts8, row pi, k-offset cb&31
      *reinterpret_cast<f16x8*>(
          &lds[H5 + ts8 * 4096 + (pi >> 4) * 512 + ((kk << 4) | (pi & 15)) * 8]) = vo;
    }
  }
  __syncthreads();   // x4 visible to all waves; stage(0,1) also drained

  // ---- L5 K-loop, NK=16; in-flight/wave: 3+3 (t<6), 3+2 (t=6), 2+2 (7..13) -
  f32x4 acc[4][4];
#pragma unroll
  for (int i = 0; i < 4; ++i)
#pragma unroll
    for (int j = 0; j < 4; ++j) acc[i][j] = (f32x4){0.f, 0.f, 0.f, 0.f};

#pragma unroll
  for (int t = 0; t < 16; ++t) {
    if (t + 2 < 16) {
      stage((t + 2) & 3, t + 2);
      if (t < 6)       VMCNT(6);
      else if (t == 6) VMCNT(5);
      else if (t < 14) VMCNT(4);
    } else if (t + 1 < 16) {
      VMCNT(2);
    } else {
      VMCNT(0);
    }
    __builtin_amdgcn_s_barrier();
    const _Float16* Ab = (t < 8) ? &lds[(t & 3) * SB] : &lds[H5 + (t - 8) * 4096];
    const _Float16* Wb2 = &lds[(t & 3) * SB + 8 * 512];
    f16x8 av[4], wv[4];
#pragma unroll
    for (int i = 0; i < 4; ++i)
      av[i] = *reinterpret_cast<const f16x8*>(Ab + (wr * 4 + i) * 512 + lane * 8);
#pragma unroll
    for (int j = 0; j < 4; ++j)
      wv[j] = *reinterpret_cast<const f16x8*>(Wb2 + (wc * 4 + j) * 512 + lane * 8);
#pragma unroll
    for (int i = 0; i < 4; ++i)
#pragma unroll
      for (int j = 0; j < 4; ++j)
        acc[i][j] = __builtin_amdgcn_mfma_f32_16x16x32_f16(av[i], wv[j], acc[i][j], 0, 0, 0);
  }
  __syncthreads();   // all waves done reading H5 (x4) before overwrite

  // ---- epilogue: stage W6 into ring [0..32768), scatter h5 into H5 ---------
  {
    const _Float16* W6b = W6 + (size_t)lr * 256 + lk * 8;
#pragma unroll
    for (int q = 0; q < 8; ++q) {
      const int gg = wid * 8 + q;           // group = ob*8 + kk
      const int ob = gg >> 3, kk = gg & 7;
      gload_lds16(W6b + (size_t)16 * ob * 256 + kk * 32, &lds[gg * 512]);
    }
  }
#pragma unroll
  for (int j = 0; j < 4; ++j) {
    const int o = wc * 64 + 16 * j + lr;      // h5 col 0..255
    const float b5 = bt5[o];
    const int gcol = o >> 5;
    const int slotc = (o >> 3) & 3;
    const int elem = o & 7;
#pragma unroll
    for (int i = 0; i < 4; ++i) {
      const int rg = wr * 4 + i;              // row>>4
#pragma unroll
      for (int q = 0; q < 4; ++q) {
        const int rl = lk * 4 + q;            // row&15
        float t = acc[i][j][q] + b5;
        t = fmaxf(t, NEG * t);
        lds[H5 + (rg * 8 + gcol) * 512 + (slotc * 16 + rl) * 8 + elem] = (_Float16)t;
      }
    }
  }
  __syncthreads();   // drains W6 vmcnt + scatter lgkmcnt

  // ---- L6: 128x128, C=256; A from h5 LDS, W from W6 LDS; no barriers -------
  f32x4 acc2[4][2];
#pragma unroll
  for (int i = 0; i < 4; ++i)
#pragma unroll
    for (int j = 0; j < 2; ++j) acc2[i][j] = (f32x4){0.f, 0.f, 0.f, 0.f};
#pragma unroll
  for (int t = 0; t < 8; ++t) {
    f16x8 av[4], wv[2];
#pragma unroll
    for (int i = 0; i < 4; ++i)
      av[i] = *reinterpret_cast<const f16x8*>(&lds[H5 + ((wr * 4 + i) * 8 + t) * 512 + lane * 8]);
#pragma unroll
    for (int j = 0; j < 2; ++j)
      wv[j] = *reinterpret_cast<const f16x8*>(&lds[((wc * 2 + j) * 8 + t) * 512 + lane * 8]);
#pragma unroll
    for (int i = 0; i < 4; ++i)
#pragma unroll
      for (int j = 0; j < 2; ++j)
        acc2[i][j] = __builtin_amdgcn_mfma_f32_16x16x32_f16(av[i], wv[j], acc2[i][j], 0, 0, 0);
  }

  // ---- L7: fused 128->1 dot + lrelu ----------------------------------------
  float* dotbuf = (float*)&lds[32768];
  float rowdot[4][4];
#pragma unroll
  for (int i = 0; i < 4; ++i)
#pragma unroll
    for (int q = 0; q < 4; ++q) rowdot[i][q] = 0.f;
#pragma unroll
  for (int j = 0; j < 2; ++j) {
    const int o = wc * 32 + 16 * j + lr;
    const float bt = bt6[o];
    const float wf = w7[o];
#pragma unroll
    for (int i = 0; i < 4; ++i)
#pragma unroll
      for (int q = 0; q < 4; ++q) {
        float t = acc2[i][j][q] + bt;
        t = fmaxf(t, NEG * t);
        rowdot[i][q] += t * wf;
      }
  }
#pragma unroll
  for (int i = 0; i < 4; ++i)
#pragma unroll
    for (int q = 0; q < 4; ++q) {
#pragma unroll
      for (int off = 1; off < 16; off <<= 1)
        rowdot[i][q] += __shfl_xor(rowdot[i][q], off, 16);
      if (lr == 0)
        dotbuf[(wr * 64 + 16 * i + lk * 4 + q) * 4 + wc] = rowdot[i][q];
    }
  __syncthreads();
  if (tid < 128) {
    const float s = dotbuf[tid * 4 + 0] + dotbuf[tid * 4 + 1] +
                    dotbuf[tid * 4 + 2] + dotbuf[tid * 4 + 3];
    dout[bm0 + tid] = fmaxf(s, NEG * s);
  }
}

// ---------------- launch -----------------------------------------------------
extern "C" void kernel_launch(void* const* d_in, const int* in_sizes, int n_in,
                              void* d_out, int out_size, void* d_ws, size_t ws_size,
                              hipStream_t stream) {
  const float* x  = (const float*)d_in[0];
  const int* idx  = (const int*)d_in[1];
  const float* w[7];
  for (int i = 0; i < 7; ++i) w[i] = (const float*)d_in[2 + i];
  const float* bn[24];
  for (int i = 0; i < 24; ++i) bn[i] = (const float*)d_in[9 + i];

  // ws: P@0 (32KB) | Wh@32KB (~0.42MB) | z_a@1MB (16MB) | h512@17MB (32MB) | z_b@49MB (16MB)
  float* P       = (float*)d_ws;
  _Float16* Wh   = (_Float16*)((char*)d_ws + (32 << 10));
  _Float16* z_a  = (_Float16*)((char*)d_ws + (1u << 20));
  _Float16* h512 = (_Float16*)((char*)d_ws + (17u << 20));
  _Float16* z_b  = (_Float16*)((char*)d_ws + (49u << 20));

  prep_c3<<<1329, 256, 0, stream>>>(
      x, w[0], w[1], w[2], w[3], w[4], w[5],
      bn[0], bn[1], bn[2], bn[3],   bn[4], bn[5], bn[6], bn[7],
      bn[8], bn[9], bn[10], bn[11], bn[12], bn[13], bn[14], bn[15],
      bn[16], bn[17], bn[18], bn[19], bn[20], bn[21], bn[22], bn[23],
      P, Wh, z_a);

  const float* bt1 = P + 64;
  const float* bt2 = P + 192;
  const float* bt3 = P + 384;
  const float* bt4 = P + 768;
  const float* bt5 = P + 1280;
  const float* bt6 = P + 1664;
  const _Float16* W2 = Wh + 0, *W3 = Wh + 4096, *W4 = Wh + 12288,
               *W5 = Wh + 45056, *W6 = Wh + 176128;

  // L1 edge + L2 GEMM fused: z1 -> (x1 -> h512+0, z2 -> z_b ld 64)
  edge_gemm64<64><<<M_ / 128, 256, 0, stream>>>(z_a, idx, bt1, W2, h512 + 0, z_b, 64);
  // L2 edge + L3 GEMM fused: z2 -> (x2 -> h512+64, z3 -> z_a ld 128)
  edge_gemm64<128><<<M_ / 128, 256, 0, stream>>>(z_b, idx, bt2, W3, h512 + 64, z_a, 128);
  // L3 edge + L4 GEMM fused (8-wave): z3 -> (x3 -> h512+128, z4 -> z_b ld 256)
  edge_gemm_l4<<<M_ / 128, 512, 0, stream>>>(z_a, idx, bt3, W4, h512, z_b);
  // e4 + L5 + L6 + L7 fused (8-wave, x4 LDS-only): h512 + z4 -> d_out
  gemm_e4l567<<<M_ / 128, 512, 0, stream>>>(
      h512, z_b, idx, bt4, W5, bt5, W6, bt6, w[6], (float*)d_out);
}

// Round 15
// 84.815 us; speedup vs baseline: 1.1056x; 1.1056x over previous
//
#include <hip/hip_runtime.h>
#include <hip/hip_bf16.h>
#include <cstdint>
#include <cstddef>

#define EPS 1e-5f
#define NEG 0.2f

static constexpr int B_ = 8, N_ = 4096, K_ = 20, M_ = B_ * N_;  // M = 32768

typedef __attribute__((ext_vector_type(8))) _Float16 f16x8;
typedef __attribute__((ext_vector_type(4))) float f32x4;

#define VMCNT(n) asm volatile("s_waitcnt vmcnt(" #n ")" ::: "memory")

// async global->LDS, 16B per lane; LDS dest = wave-uniform base + lane*16
__device__ __forceinline__ void gload_lds16(const _Float16* g, _Float16* l) {
  __builtin_amdgcn_global_load_lds(
      (const __attribute__((address_space(1))) uint32_t*)g,
      (__attribute__((address_space(3))) uint32_t*)l, 16, 0, 0);
}

// ---------------- prep + layer-1 C=3 GEMM, one kernel ------------------------
// blocks 0..511: gemm_c3 ; 512..1327: weight fold ; 1328: BN param table
__global__ __launch_bounds__(256) void prep_c3(
    const float* __restrict__ x, const float* __restrict__ w1,
    const float* __restrict__ w2, const float* __restrict__ w3,
    const float* __restrict__ w4, const float* __restrict__ w5,
    const float* __restrict__ w6,
    const float* __restrict__ g1, const float* __restrict__ b1, const float* __restrict__ m1, const float* __restrict__ v1,
    const float* __restrict__ g2, const float* __restrict__ b2, const float* __restrict__ m2, const float* __restrict__ v2,
    const float* __restrict__ g3, const float* __restrict__ b3, const float* __restrict__ m3, const float* __restrict__ v3,
    const float* __restrict__ g4, const float* __restrict__ b4, const float* __restrict__ m4, const float* __restrict__ v4,
    const float* __restrict__ g5, const float* __restrict__ b5, const float* __restrict__ m5, const float* __restrict__ v5,
    const float* __restrict__ g6, const float* __restrict__ b6, const float* __restrict__ m6, const float* __restrict__ v6,
    float* __restrict__ P, _Float16* __restrict__ Wh, _Float16* __restrict__ z) {
  const int bid = blockIdx.x, tid = threadIdx.x;
  if (bid < 512) {
    const int o  = tid & 63;
    const int pi = tid >> 6;
    const float ww0 = w1[o * 3 + 0], ww1 = w1[o * 3 + 1], ww2 = w1[o * 3 + 2];
    const float iv = g1[o] * rsqrtf(v1[o] + EPS);
    const int pbase = bid * 64;
    const int b = pbase >> 12;
    const int nbase = pbase & (N_ - 1);
    const float* xb = x + (size_t)b * 3 * N_;
    for (int pj = pi; pj < 64; pj += 4) {
      const int n = nbase + pj;
      const float x0 = xb[n], x1v = xb[N_ + n], x2v = xb[2 * N_ + n];
      z[(size_t)(pbase + pj) * 64 + o] = (_Float16)((x0 * ww0 + x1v * ww1 + x2v * ww2) * iv);
    }
    return;
  }
  if (bid == 1328) {
    const float* G[6]  = {g1, g2, g3, g4, g5, g6};
    const float* Bb[6] = {b1, b2, b3, b4, b5, b6};
    const float* Mm[6] = {m1, m2, m3, m4, m5, m6};
    const float* Vv[6] = {v1, v2, v3, v4, v5, v6};
    const int Cs[6] = {64, 64, 128, 256, 256, 128};
    const int OI[6] = {0, 128, 256, 512, 1024, 1536};
    const int OB[6] = {64, 192, 384, 768, 1280, 1664};
    for (int l = 0; l < 6; ++l) {
      for (int c = tid; c < Cs[l]; c += 256) {
        float iv = G[l][c] * rsqrtf(Vv[l][c] + EPS);
        P[OI[l] + c] = iv;
        P[OB[l] + c] = Bb[l][c] - Mm[l][c] * iv;
      }
    }
    return;
  }
  const int fb = bid - 512;
  const float* w; const float* g; const float* v; _Float16* dst; int lc, base;
  if (fb < 16)       { w = w2; g = g2; v = v2; dst = Wh + 0;      lc = 6; base = 0;   }
  else if (fb < 48)  { w = w3; g = g3; v = v3; dst = Wh + 4096;   lc = 6; base = 16;  }
  else if (fb < 176) { w = w4; g = g4; v = v4; dst = Wh + 12288;  lc = 7; base = 48;  }
  else if (fb < 688) { w = w5; g = g5; v = v5; dst = Wh + 45056;  lc = 9; base = 176; }
  else               { w = w6; g = g6; v = v6; dst = Wh + 176128; lc = 8; base = 688; }
  const int e = (fb - base) * 256 + tid;
  const int o = e >> lc;
  dst[e] = (_Float16)(w[e] * (g[o] * rsqrtf(v[o] + EPS)));
}

// ---------------- fused edge(C=64) + small GEMM, 8-wave ----------------------
// 512 thr; edge: TPP=8, 64 points/pass, 2 passes. GEMM wave grid 2x4.
template <int BO>
__global__ __launch_bounds__(512) void edge_gemm64(
    const _Float16* __restrict__ z, const int* __restrict__ idx,
    const float* __restrict__ betap,
    const _Float16* __restrict__ W,           // (BO, 64) inv-folded
    _Float16* __restrict__ hout,              // h512 column base (ld 512)
    _Float16* __restrict__ zout, int ldzout) {
  constexpr int GW = BO / 8;
  constexpr int OJ = BO / 64;                 // per-wave col frags (wc in 0..3)
  __shared__ _Float16 Asmem[128 * 64];
  __shared__ _Float16 Wsmem[BO * 64];

  const int tid = threadIdx.x, lane = tid & 63, wid = tid >> 6;
  const int batch = blockIdx.x & 7, chunk = blockIdx.x >> 3;
  const int bm0 = (batch << 12) + chunk * 128;
  const int lr = lane & 15, lk = lane >> 4;

  const _Float16* Wbase = W + (size_t)lr * 64 + lk * 8;
#pragma unroll
  for (int g = wid; g < GW; g += 8) {
    const int o = g >> 1, s = g & 1;
    gload_lds16(Wbase + (size_t)16 * o * 64 + s * 32, Wsmem + g * 512);
  }

  const int lid = tid & 7, cb = lid * 8;
  float bt[8];
#pragma unroll
  for (int q = 0; q < 8; ++q) bt[q] = betap[cb + q];
  const _Float16* zb = z + ((size_t)(batch << 12)) * 64;
#pragma unroll
  for (int pass = 0; pass < 2; ++pass) {
    const int pi = pass * 64 + (tid >> 3);
    const int p = bm0 + pi;
    const int* ip = idx + (size_t)p * K_;
    const int ir0 = ip[lid];
    const int ir1 = ip[8 + lid];
    const int ir2 = ip[16 + (lid & 3)];
    f16x8 mx = *reinterpret_cast<const f16x8*>(zb + (size_t)__shfl(ir0, 0, 8) * 64 + cb);
#pragma unroll
    for (int k = 1; k < K_; ++k) {
      const int g = (k < 8) ? __shfl(ir0, k, 8)
                  : (k < 16) ? __shfl(ir1, k - 8, 8)
                             : __shfl(ir2, k - 16, 8);
      const f16x8 v = *reinterpret_cast<const f16x8*>(zb + (size_t)g * 64 + cb);
#pragma unroll
      for (int q = 0; q < 8; ++q) mx[q] = v[q] > mx[q] ? v[q] : mx[q];
    }
    const f16x8 vc = *reinterpret_cast<const f16x8*>(z + (size_t)p * 64 + cb);
    f16x8 vo;
#pragma unroll
    for (int q = 0; q < 8; ++q) {
      const float e = (float)mx[q] - (float)vc[q] + bt[q];
      vo[q] = (_Float16)fmaxf(e, NEG * e);
    }
    *reinterpret_cast<f16x8*>(hout + (size_t)p * 512 + cb) = vo;
    const int i = pi >> 4, rr = pi & 15, s = cb >> 5, kk = (cb >> 3) & 3;
    *reinterpret_cast<f16x8*>(Asmem + (i * 2 + s) * 512 + ((kk << 4) | rr) * 8) = vo;
  }
  __syncthreads();

  // GEMM: 8 waves 2x4; per-wave 64 rows x BO/4 cols; 2 K-halves
  const int wr = wid >> 2, wc = wid & 3;
  f32x4 acc[4][OJ];
#pragma unroll
  for (int i = 0; i < 4; ++i)
#pragma unroll
    for (int j = 0; j < OJ; ++j) acc[i][j] = (f32x4){0.f, 0.f, 0.f, 0.f};
#pragma unroll
  for (int s = 0; s < 2; ++s) {
    f16x8 av[4], wv[OJ];
#pragma unroll
    for (int i = 0; i < 4; ++i)
      av[i] = *reinterpret_cast<const f16x8*>(Asmem + ((wr * 4 + i) * 2 + s) * 512 + lane * 8);
#pragma unroll
    for (int j = 0; j < OJ; ++j)
      wv[j] = *reinterpret_cast<const f16x8*>(Wsmem + ((wc * OJ + j) * 2 + s) * 512 + lane * 8);
#pragma unroll
    for (int i = 0; i < 4; ++i)
#pragma unroll
      for (int j = 0; j < OJ; ++j)
        acc[i][j] = __builtin_amdgcn_mfma_f32_16x16x32_f16(av[i], wv[j], acc[i][j], 0, 0, 0);
  }

#pragma unroll
  for (int j = 0; j < OJ; ++j) {
    const int o = wc * (BO / 4) + 16 * j + lr;
#pragma unroll
    for (int i = 0; i < 4; ++i) {
      const int r0 = bm0 + wr * 64 + 16 * i + lk * 4;
#pragma unroll
      for (int q = 0; q < 4; ++q)
        zout[(size_t)(r0 + q) * ldzout + o] = (_Float16)acc[i][j][q];
    }
  }
}

// ---------------- L4: edge(C=128) in regs + 8-wave GEMM (128x256, C=128) -----
__global__ __launch_bounds__(512, 1) void edge_gemm_l4(
    const _Float16* __restrict__ z3,          // (M,128)
    const int* __restrict__ idx,
    const float* __restrict__ btE,            // edge beta (128)
    const _Float16* __restrict__ W4,          // (256,128)
    _Float16* __restrict__ h512,              // x3 -> cols 128..255
    _Float16* __restrict__ z4out) {           // (M,256)
  constexpr int SB = 24 * 512;                // 8 A-groups + 16 W-groups per K-step
  __shared__ _Float16 lds[4 * SB];            // 96 KB

  const int tid = threadIdx.x, lane = tid & 63, wid = tid >> 6;
  const int wr = wid >> 2, wc = wid & 3;
  const int bid = blockIdx.x, batch = bid & 7;
  const int bm0 = (batch << 12) + (bid >> 3) * 128;
  const int lr = lane & 15, lk = lane >> 4;

  // upfront W4 staging: 64 groups (ob 0..15, kk 0..3), 8 per wave
  const _Float16* Wb = W4 + (size_t)lr * 128 + lk * 8;
#pragma unroll
  for (int q = 0; q < 8; ++q) {
    const int gg = wid * 8 + q;
    const int ob = gg >> 2, kk = gg & 3;
    gload_lds16(Wb + (size_t)16 * ob * 128 + kk * 32, &lds[kk * SB + (8 + ob) * 512]);
  }

  // edge phase: TPP=16, 32 points/pass, 4 passes
  const int lid = tid & 15, cb = lid * 8;
  float bt[8];
#pragma unroll
  for (int q = 0; q < 8; ++q) bt[q] = btE[cb + q];
  const _Float16* zb = z3 + ((size_t)(batch << 12)) * 128;
  f16x8 x3r[4];
#pragma unroll
  for (int pass = 0; pass < 4; ++pass) {
    const int pi = pass * 32 + (tid >> 4);
    const int p = bm0 + pi;
    const int* ip = idx + (size_t)p * K_;
    const int ir0 = ip[lid];
    const int ir1 = (lid < 4) ? ip[16 + lid] : 0;
    f16x8 mx = *reinterpret_cast<const f16x8*>(zb + (size_t)__shfl(ir0, 0, 16) * 128 + cb);
#pragma unroll
    for (int k = 1; k < K_; ++k) {
      const int g = (k < 16) ? __shfl(ir0, k, 16) : __shfl(ir1, k - 16, 16);
      const f16x8 v = *reinterpret_cast<const f16x8*>(zb + (size_t)g * 128 + cb);
#pragma unroll
      for (int q = 0; q < 8; ++q) mx[q] = v[q] > mx[q] ? v[q] : mx[q];
    }
    const f16x8 vc = *reinterpret_cast<const f16x8*>(z3 + (size_t)p * 128 + cb);
    f16x8 vo;
#pragma unroll
    for (int q = 0; q < 8; ++q) {
      const float e = (float)mx[q] - (float)vc[q] + bt[q];
      vo[q] = (_Float16)fmaxf(e, NEG * e);
    }
    x3r[pass] = vo;
    *reinterpret_cast<f16x8*>(h512 + (size_t)p * 512 + 128 + cb) = vo;
  }
  // ds_write A fragments for all 4 K-step buffers
  {
    const int kk = (cb >> 3) & 3;
    const int ts = cb >> 5;                 // K-step 0..3
    const int rr = (tid >> 4) & 15;
#pragma unroll
    for (int pp = 0; pp < 4; ++pp) {
      const int grp = pp * 2 + (tid >> 8);
      *reinterpret_cast<f16x8*>(&lds[ts * SB + grp * 512 + ((kk << 4) | rr) * 8]) = x3r[pp];
    }
  }
  __syncthreads();   // drains vmcnt (W) + lgkmcnt (A writes)

  // GEMM: NK=4, all resident, no further barriers
  f32x4 acc[4][4];
#pragma unroll
  for (int i = 0; i < 4; ++i)
#pragma unroll
    for (int j = 0; j < 4; ++j) acc[i][j] = (f32x4){0.f, 0.f, 0.f, 0.f};
#pragma unroll
  for (int t = 0; t < 4; ++t) {
    f16x8 av[4], wv[4];
#pragma unroll
    for (int i = 0; i < 4; ++i)
      av[i] = *reinterpret_cast<const f16x8*>(&lds[t * SB + (wr * 4 + i) * 512 + lane * 8]);
#pragma unroll
    for (int j = 0; j < 4; ++j)
      wv[j] = *reinterpret_cast<const f16x8*>(&lds[t * SB + (8 + wc * 4 + j) * 512 + lane * 8]);
#pragma unroll
    for (int i = 0; i < 4; ++i)
#pragma unroll
      for (int j = 0; j < 4; ++j)
        acc[i][j] = __builtin_amdgcn_mfma_f32_16x16x32_f16(av[i], wv[j], acc[i][j], 0, 0, 0);
  }

#pragma unroll
  for (int j = 0; j < 4; ++j) {
    const int o = wc * 64 + 16 * j + lr;
#pragma unroll
    for (int i = 0; i < 4; ++i) {
      const int r0 = bm0 + wr * 64 + 16 * i + lk * 4;
#pragma unroll
      for (int q = 0; q < 4; ++q)
        z4out[(size_t)(r0 + q) * 256 + o] = (_Float16)acc[i][j][q];
    }
  }
}

// ---------------- edge max, standalone (O=256) -------------------------------
template <int O>
__global__ __launch_bounds__(256) void edge_max8(
    const _Float16* __restrict__ z, const int* __restrict__ idx,
    const float* __restrict__ betap, _Float16* __restrict__ out, int ldout) {
  constexpr int TPP = O / 8;
  constexpr int PPB = 256 / TPP;
  constexpr int NW = (K_ + TPP - 1) / TPP;
  const int t = threadIdx.x;
  const int batch = blockIdx.x & 7;
  const int chunk = blockIdx.x >> 3;
  const int p = (batch << 12) + chunk * PPB + t / TPP;
  const int lid = t % TPP;
  const int cb = lid * 8;
  const int* ip = idx + (size_t)p * K_;
  int ir[NW];
#pragma unroll
  for (int wv = 0; wv < NW; ++wv) {
    const int l = wv * TPP + lid;
    ir[wv] = (l < K_) ? ip[l] : ip[0];
  }
  const _Float16* zb = z + ((size_t)(batch << 12)) * O;

  f16x8 mx = *reinterpret_cast<const f16x8*>(zb + (size_t)__shfl(ir[0], 0, TPP) * O + cb);
#pragma unroll
  for (int k = 1; k < K_; ++k) {
    const int g = __shfl(ir[k / TPP], k % TPP, TPP);
    const f16x8 v = *reinterpret_cast<const f16x8*>(zb + (size_t)g * O + cb);
#pragma unroll
    for (int q = 0; q < 8; ++q) mx[q] = v[q] > mx[q] ? v[q] : mx[q];
  }
  const f16x8 vc = *reinterpret_cast<const f16x8*>(z + (size_t)p * O + cb);
  f16x8 vo;
#pragma unroll
  for (int q = 0; q < 8; ++q) {
    const float e = (float)mx[q] - (float)vc[q] + betap[cb + q];
    vo[q] = (_Float16)fmaxf(e, NEG * e);
  }
  *reinterpret_cast<f16x8*>(out + (size_t)p * ldout + cb) = vo;
}

// ---------------- L5+L6+L7 fused, 8-wave (R13 structure) ---------------------
__global__ __launch_bounds__(512, 1) void gemm_l567(
    const _Float16* __restrict__ A,           // h512, ld 512
    const _Float16* __restrict__ W5,          // (256,512)
    const float* __restrict__ bt5,
    const _Float16* __restrict__ W6,          // (128,256)
    const float* __restrict__ bt6,
    const float* __restrict__ w7,             // (128)
    float* __restrict__ dout) {               // (M)
  constexpr int SB = 24 * 512;                // halves per ring buffer (24KB)
  constexpr int H5 = 4 * SB;                  // h5 frag region offset (halves)
  __shared__ _Float16 lds[4 * SB + 32768];    // 96KB + 64KB = 160KB

  const int tid = threadIdx.x, lane = tid & 63, wid = tid >> 6;
  const int wr = wid >> 2, wc = wid & 3;
  const int bid = blockIdx.x;
  const int bm0 = ((bid & 7) << 12) + (bid >> 3) * 128;  // batch-XCD swizzle
  const int lr = lane & 15, lk = lane >> 4;

  const _Float16* Abase = A + (size_t)(bm0 + lr) * 512 + lk * 8;
  const _Float16* W5b = W5 + (size_t)lr * 512 + lk * 8;

  f32x4 acc[4][4];
#pragma unroll
  for (int i = 0; i < 4; ++i)
#pragma unroll
    for (int j = 0; j < 4; ++j) acc[i][j] = (f32x4){0.f, 0.f, 0.f, 0.f};

  auto stage = [&](int buf, int k0) {
    _Float16* dst = &lds[buf * SB];
#pragma unroll
    for (int q = 0; q < 3; ++q) {
      const int g = wid * 3 + q;
      const _Float16* src = (g < 8)
          ? Abase + (size_t)16 * g * 512 + k0
          : W5b + (size_t)16 * (g - 8) * 512 + k0;
      gload_lds16(src, dst + g * 512);
    }
  };

  stage(0, 0);
  stage(1, 32);
#pragma unroll
  for (int t = 0; t < 16; ++t) {
    if (t + 2 < 16) {
      stage((t + 2) & 3, (t + 2) * 32);
      VMCNT(6);
    } else if (t + 1 < 16) {
      VMCNT(3);
    } else {
      VMCNT(0);
    }
    __builtin_amdgcn_s_barrier();
    const _Float16* Ab = &lds[(t & 3) * SB];
    f16x8 av[4], wv[4];
#pragma unroll
    for (int i = 0; i < 4; ++i)
      av[i] = *reinterpret_cast<const f16x8*>(Ab + (wr * 4 + i) * 512 + lane * 8);
#pragma unroll
    for (int j = 0; j < 4; ++j)
      wv[j] = *reinterpret_cast<const f16x8*>(Ab + (8 + wc * 4 + j) * 512 + lane * 8);
#pragma unroll
    for (int i = 0; i < 4; ++i)
#pragma unroll
      for (int j = 0; j < 4; ++j)
        acc[i][j] = __builtin_amdgcn_mfma_f32_16x16x32_f16(av[i], wv[j], acc[i][j], 0, 0, 0);
  }

  // ---- epilogue: stage W6 into free ring [0..32768), scatter h5 into [H5..)
  {
    const _Float16* W6b = W6 + (size_t)lr * 256 + lk * 8;
#pragma unroll
    for (int q = 0; q < 8; ++q) {
      const int gg = wid * 8 + q;           // 0..63: group = ob*8 + kk
      const int ob = gg >> 3, kk = gg & 7;
      gload_lds16(W6b + (size_t)16 * ob * 256 + kk * 32, &lds[gg * 512]);
    }
  }
#pragma unroll
  for (int j = 0; j < 4; ++j) {
    const int o = wc * 64 + 16 * j + lr;      // h5 col 0..255
    const float b5 = bt5[o];
    const int gcol = o >> 5;
    const int slotc = (o >> 3) & 3;
    const int elem = o & 7;
#pragma unroll
    for (int i = 0; i < 4; ++i) {
      const int rg = wr * 4 + i;              // row>>4
#pragma unroll
      for (int q = 0; q < 4; ++q) {
        const int rl = lk * 4 + q;            // row&15
        float t = acc[i][j][q] + b5;
        t = fmaxf(t, NEG * t);
        lds[H5 + (rg * 8 + gcol) * 512 + (slotc * 16 + rl) * 8 + elem] = (_Float16)t;
      }
    }
  }
  __syncthreads();   // drains W6 vmcnt + scatter lgkmcnt

  // ---- L6: 128x128, C=256; A from h5 LDS, W from W6 LDS; no barriers
  f32x4 acc2[4][2];
#pragma unroll
  for (int i = 0; i < 4; ++i)
#pragma unroll
    for (int j = 0; j < 2; ++j) acc2[i][j] = (f32x4){0.f, 0.f, 0.f, 0.f};
#pragma unroll
  for (int t = 0; t < 8; ++t) {
    f16x8 av[4], wv[2];
#pragma unroll
    for (int i = 0; i < 4; ++i)
      av[i] = *reinterpret_cast<const f16x8*>(&lds[H5 + ((wr * 4 + i) * 8 + t) * 512 + lane * 8]);
#pragma unroll
    for (int j = 0; j < 2; ++j)
      wv[j] = *reinterpret_cast<const f16x8*>(&lds[((wc * 2 + j) * 8 + t) * 512 + lane * 8]);
#pragma unroll
    for (int i = 0; i < 4; ++i)
#pragma unroll
      for (int j = 0; j < 2; ++j)
        acc2[i][j] = __builtin_amdgcn_mfma_f32_16x16x32_f16(av[i], wv[j], acc2[i][j], 0, 0, 0);
  }

  // ---- L7: fused 128->1 dot + lrelu
  float* dotbuf = (float*)&lds[32768];        // 2KB in spare ring space
  float rowdot[4][4];
#pragma unroll
  for (int i = 0; i < 4; ++i)
#pragma unroll
    for (int q = 0; q < 4; ++q) rowdot[i][q] = 0.f;
#pragma unroll
  for (int j = 0; j < 2; ++j) {
    const int o = wc * 32 + 16 * j + lr;
    const float bt = bt6[o];
    const float wf = w7[o];
#pragma unroll
    for (int i = 0; i < 4; ++i)
#pragma unroll
      for (int q = 0; q < 4; ++q) {
        float t = acc2[i][j][q] + bt;
        t = fmaxf(t, NEG * t);
        rowdot[i][q] += t * wf;
      }
  }
#pragma unroll
  for (int i = 0; i < 4; ++i)
#pragma unroll
    for (int q = 0; q < 4; ++q) {
#pragma unroll
      for (int off = 1; off < 16; off <<= 1)
        rowdot[i][q] += __shfl_xor(rowdot[i][q], off, 16);
      if (lr == 0)
        dotbuf[(wr * 64 + 16 * i + lk * 4 + q) * 4 + wc] = rowdot[i][q];
    }
  __syncthreads();
  if (tid < 128) {
    const float s = dotbuf[tid * 4 + 0] + dotbuf[tid * 4 + 1] +
                    dotbuf[tid * 4 + 2] + dotbuf[tid * 4 + 3];
    dout[bm0 + tid] = fmaxf(s, NEG * s);
  }
}

// ---------------- launch -----------------------------------------------------
extern "C" void kernel_launch(void* const* d_in, const int* in_sizes, int n_in,
                              void* d_out, int out_size, void* d_ws, size_t ws_size,
                              hipStream_t stream) {
  const float* x  = (const float*)d_in[0];
  const int* idx  = (const int*)d_in[1];
  const float* w[7];
  for (int i = 0; i < 7; ++i) w[i] = (const float*)d_in[2 + i];
  const float* bn[24];
  for (int i = 0; i < 24; ++i) bn[i] = (const float*)d_in[9 + i];

  // ws: P@0 (32KB) | Wh@32KB (~0.42MB) | z_a@1MB (16MB) | h512@17MB (32MB) | z_b@49MB (16MB)
  float* P       = (float*)d_ws;
  _Float16* Wh   = (_Float16*)((char*)d_ws + (32 << 10));
  _Float16* z_a  = (_Float16*)((char*)d_ws + (1u << 20));
  _Float16* h512 = (_Float16*)((char*)d_ws + (17u << 20));
  _Float16* z_b  = (_Float16*)((char*)d_ws + (49u << 20));

  prep_c3<<<1329, 256, 0, stream>>>(
      x, w[0], w[1], w[2], w[3], w[4], w[5],
      bn[0], bn[1], bn[2], bn[3],   bn[4], bn[5], bn[6], bn[7],
      bn[8], bn[9], bn[10], bn[11], bn[12], bn[13], bn[14], bn[15],
      bn[16], bn[17], bn[18], bn[19], bn[20], bn[21], bn[22], bn[23],
      P, Wh, z_a);

  const float* bt1 = P + 64;
  const float* bt2 = P + 192;
  const float* bt3 = P + 384;
  const float* bt4 = P + 768;
  const float* bt5 = P + 1280;
  const float* bt6 = P + 1664;
  const _Float16* W2 = Wh + 0, *W3 = Wh + 4096, *W4 = Wh + 12288,
               *W5 = Wh + 45056, *W6 = Wh + 176128;

  // L1 edge + L2 GEMM fused (8-wave): z1 -> (x1 -> h512+0, z2 -> z_b ld 64)
  edge_gemm64<64><<<M_ / 128, 512, 0, stream>>>(z_a, idx, bt1, W2, h512 + 0, z_b, 64);
  // L2 edge + L3 GEMM fused (8-wave): z2 -> (x2 -> h512+64, z3 -> z_a ld 128)
  edge_gemm64<128><<<M_ / 128, 512, 0, stream>>>(z_b, idx, bt2, W3, h512 + 64, z_a, 128);
  // L3 edge + L4 GEMM fused (8-wave): z3 -> (x3 -> h512+128, z4 -> z_b ld 256)
  edge_gemm_l4<<<M_ / 128, 512, 0, stream>>>(z_a, idx, bt3, W4, h512, z_b);
  // L4 edge: z4 -> x4 (h512+256)
  edge_max8<256><<<M_ / 8, 256, 0, stream>>>(z_b, idx, bt4, h512 + 256, 512);
  // L5+L6+L7 fused (8-wave, LDS handoff): h512 -> d_out
  gemm_l567<<<M_ / 128, 512, 0, stream>>>(
      h512, W5, bt5, W6, bt6, w[6], (float*)d_out);
}

// Round 16
// 84.721 us; speedup vs baseline: 1.1068x; 1.0011x over previous
//
#include <hip/hip_runtime.h>
#include <hip/hip_bf16.h>
#include <cstdint>
#include <cstddef>

#define EPS 1e-5f
#define NEG 0.2f

static constexpr int B_ = 8, N_ = 4096, K_ = 20, M_ = B_ * N_;  // M = 32768

typedef __attribute__((ext_vector_type(8))) _Float16 f16x8;
typedef __attribute__((ext_vector_type(4))) float f32x4;

#define VMCNT(n) asm volatile("s_waitcnt vmcnt(" #n ")" ::: "memory")

// async global->LDS, 16B per lane; LDS dest = wave-uniform base + lane*16
__device__ __forceinline__ void gload_lds16(const _Float16* g, _Float16* l) {
  __builtin_amdgcn_global_load_lds(
      (const __attribute__((address_space(1))) uint32_t*)g,
      (__attribute__((address_space(3))) uint32_t*)l, 16, 0, 0);
}

// ---------------- prep + layer-1 C=3 GEMM, one kernel ------------------------
// blocks 0..511: gemm_c3 ; 512..1327: weight fold ; 1328: BN param table
__global__ __launch_bounds__(256) void prep_c3(
    const float* __restrict__ x, const float* __restrict__ w1,
    const float* __restrict__ w2, const float* __restrict__ w3,
    const float* __restrict__ w4, const float* __restrict__ w5,
    const float* __restrict__ w6,
    const float* __restrict__ g1, const float* __restrict__ b1, const float* __restrict__ m1, const float* __restrict__ v1,
    const float* __restrict__ g2, const float* __restrict__ b2, const float* __restrict__ m2, const float* __restrict__ v2,
    const float* __restrict__ g3, const float* __restrict__ b3, const float* __restrict__ m3, const float* __restrict__ v3,
    const float* __restrict__ g4, const float* __restrict__ b4, const float* __restrict__ m4, const float* __restrict__ v4,
    const float* __restrict__ g5, const float* __restrict__ b5, const float* __restrict__ m5, const float* __restrict__ v5,
    const float* __restrict__ g6, const float* __restrict__ b6, const float* __restrict__ m6, const float* __restrict__ v6,
    float* __restrict__ P, _Float16* __restrict__ Wh, _Float16* __restrict__ z) {
  const int bid = blockIdx.x, tid = threadIdx.x;
  if (bid < 512) {
    const int o  = tid & 63;
    const int pi = tid >> 6;
    const float ww0 = w1[o * 3 + 0], ww1 = w1[o * 3 + 1], ww2 = w1[o * 3 + 2];
    const float iv = g1[o] * rsqrtf(v1[o] + EPS);
    const int pbase = bid * 64;
    const int b = pbase >> 12;
    const int nbase = pbase & (N_ - 1);
    const float* xb = x + (size_t)b * 3 * N_;
    for (int pj = pi; pj < 64; pj += 4) {
      const int n = nbase + pj;
      const float x0 = xb[n], x1v = xb[N_ + n], x2v = xb[2 * N_ + n];
      z[(size_t)(pbase + pj) * 64 + o] = (_Float16)((x0 * ww0 + x1v * ww1 + x2v * ww2) * iv);
    }
    return;
  }
  if (bid == 1328) {
    const float* G[6]  = {g1, g2, g3, g4, g5, g6};
    const float* Bb[6] = {b1, b2, b3, b4, b5, b6};
    const float* Mm[6] = {m1, m2, m3, m4, m5, m6};
    const float* Vv[6] = {v1, v2, v3, v4, v5, v6};
    const int Cs[6] = {64, 64, 128, 256, 256, 128};
    const int OI[6] = {0, 128, 256, 512, 1024, 1536};
    const int OB[6] = {64, 192, 384, 768, 1280, 1664};
    for (int l = 0; l < 6; ++l) {
      for (int c = tid; c < Cs[l]; c += 256) {
        float iv = G[l][c] * rsqrtf(Vv[l][c] + EPS);
        P[OI[l] + c] = iv;
        P[OB[l] + c] = Bb[l][c] - Mm[l][c] * iv;
      }
    }
    return;
  }
  const int fb = bid - 512;
  const float* w; const float* g; const float* v; _Float16* dst; int lc, base;
  if (fb < 16)       { w = w2; g = g2; v = v2; dst = Wh + 0;      lc = 6; base = 0;   }
  else if (fb < 48)  { w = w3; g = g3; v = v3; dst = Wh + 4096;   lc = 6; base = 16;  }
  else if (fb < 176) { w = w4; g = g4; v = v4; dst = Wh + 12288;  lc = 7; base = 48;  }
  else if (fb < 688) { w = w5; g = g5; v = v5; dst = Wh + 45056;  lc = 9; base = 176; }
  else               { w = w6; g = g6; v = v6; dst = Wh + 176128; lc = 8; base = 688; }
  const int e = (fb - base) * 256 + tid;
  const int o = e >> lc;
  dst[e] = (_Float16)(w[e] * (g[o] * rsqrtf(v[o] + EPS)));
}

// ---------------- fused edge(C=64) + small GEMM, 8-wave ----------------------
template <int BO>
__global__ __launch_bounds__(512) void edge_gemm64(
    const _Float16* __restrict__ z, const int* __restrict__ idx,
    const float* __restrict__ betap,
    const _Float16* __restrict__ W,           // (BO, 64) inv-folded
    _Float16* __restrict__ hout,              // h512 column base (ld 512)
    _Float16* __restrict__ zout, int ldzout) {
  constexpr int GW = BO / 8;
  constexpr int OJ = BO / 64;
  __shared__ _Float16 Asmem[128 * 64];
  __shared__ _Float16 Wsmem[BO * 64];

  const int tid = threadIdx.x, lane = tid & 63, wid = tid >> 6;
  const int batch = blockIdx.x & 7, chunk = blockIdx.x >> 3;
  const int bm0 = (batch << 12) + chunk * 128;
  const int lr = lane & 15, lk = lane >> 4;

  const _Float16* Wbase = W + (size_t)lr * 64 + lk * 8;
#pragma unroll
  for (int g = wid; g < GW; g += 8) {
    const int o = g >> 1, s = g & 1;
    gload_lds16(Wbase + (size_t)16 * o * 64 + s * 32, Wsmem + g * 512);
  }

  const int lid = tid & 7, cb = lid * 8;
  float bt[8];
#pragma unroll
  for (int q = 0; q < 8; ++q) bt[q] = betap[cb + q];
  const _Float16* zb = z + ((size_t)(batch << 12)) * 64;
#pragma unroll
  for (int pass = 0; pass < 2; ++pass) {
    const int pi = pass * 64 + (tid >> 3);
    const int p = bm0 + pi;
    const int* ip = idx + (size_t)p * K_;
    const int ir0 = ip[lid];
    const int ir1 = ip[8 + lid];
    const int ir2 = ip[16 + (lid & 3)];
    f16x8 mx = *reinterpret_cast<const f16x8*>(zb + (size_t)__shfl(ir0, 0, 8) * 64 + cb);
#pragma unroll
    for (int k = 1; k < K_; ++k) {
      const int g = (k < 8) ? __shfl(ir0, k, 8)
                  : (k < 16) ? __shfl(ir1, k - 8, 8)
                             : __shfl(ir2, k - 16, 8);
      const f16x8 v = *reinterpret_cast<const f16x8*>(zb + (size_t)g * 64 + cb);
#pragma unroll
      for (int q = 0; q < 8; ++q) mx[q] = v[q] > mx[q] ? v[q] : mx[q];
    }
    const f16x8 vc = *reinterpret_cast<const f16x8*>(z + (size_t)p * 64 + cb);
    f16x8 vo;
#pragma unroll
    for (int q = 0; q < 8; ++q) {
      const float e = (float)mx[q] - (float)vc[q] + bt[q];
      vo[q] = (_Float16)fmaxf(e, NEG * e);
    }
    *reinterpret_cast<f16x8*>(hout + (size_t)p * 512 + cb) = vo;
    const int i = pi >> 4, rr = pi & 15, s = cb >> 5, kk = (cb >> 3) & 3;
    *reinterpret_cast<f16x8*>(Asmem + (i * 2 + s) * 512 + ((kk << 4) | rr) * 8) = vo;
  }
  __syncthreads();

  const int wr = wid >> 2, wc = wid & 3;
  f32x4 acc[4][OJ];
#pragma unroll
  for (int i = 0; i < 4; ++i)
#pragma unroll
    for (int j = 0; j < OJ; ++j) acc[i][j] = (f32x4){0.f, 0.f, 0.f, 0.f};
  __builtin_amdgcn_s_setprio(1);
#pragma unroll
  for (int s = 0; s < 2; ++s) {
    f16x8 av[4], wv[OJ];
#pragma unroll
    for (int i = 0; i < 4; ++i)
      av[i] = *reinterpret_cast<const f16x8*>(Asmem + ((wr * 4 + i) * 2 + s) * 512 + lane * 8);
#pragma unroll
    for (int j = 0; j < OJ; ++j)
      wv[j] = *reinterpret_cast<const f16x8*>(Wsmem + ((wc * OJ + j) * 2 + s) * 512 + lane * 8);
#pragma unroll
    for (int i = 0; i < 4; ++i)
#pragma unroll
      for (int j = 0; j < OJ; ++j)
        acc[i][j] = __builtin_amdgcn_mfma_f32_16x16x32_f16(av[i], wv[j], acc[i][j], 0, 0, 0);
  }
  __builtin_amdgcn_s_setprio(0);

#pragma unroll
  for (int j = 0; j < OJ; ++j) {
    const int o = wc * (BO / 4) + 16 * j + lr;
#pragma unroll
    for (int i = 0; i < 4; ++i) {
      const int r0 = bm0 + wr * 64 + 16 * i + lk * 4;
#pragma unroll
      for (int q = 0; q < 4; ++q)
        zout[(size_t)(r0 + q) * ldzout + o] = (_Float16)acc[i][j][q];
    }
  }
}

// ---------------- L4: edge(C=128) in regs + 8-wave GEMM (128x256, C=128) -----
__global__ __launch_bounds__(512, 1) void edge_gemm_l4(
    const _Float16* __restrict__ z3,          // (M,128)
    const int* __restrict__ idx,
    const float* __restrict__ btE,            // edge beta (128)
    const _Float16* __restrict__ W4,          // (256,128)
    _Float16* __restrict__ h512,              // x3 -> cols 128..255
    _Float16* __restrict__ z4out) {           // (M,256)
  constexpr int SB = 24 * 512;
  __shared__ _Float16 lds[4 * SB];            // 96 KB

  const int tid = threadIdx.x, lane = tid & 63, wid = tid >> 6;
  const int wr = wid >> 2, wc = wid & 3;
  const int bid = blockIdx.x, batch = bid & 7;
  const int bm0 = (batch << 12) + (bid >> 3) * 128;
  const int lr = lane & 15, lk = lane >> 4;

  const _Float16* Wb = W4 + (size_t)lr * 128 + lk * 8;
#pragma unroll
  for (int q = 0; q < 8; ++q) {
    const int gg = wid * 8 + q;
    const int ob = gg >> 2, kk = gg & 3;
    gload_lds16(Wb + (size_t)16 * ob * 128 + kk * 32, &lds[kk * SB + (8 + ob) * 512]);
  }

  const int lid = tid & 15, cb = lid * 8;
  float bt[8];
#pragma unroll
  for (int q = 0; q < 8; ++q) bt[q] = btE[cb + q];
  const _Float16* zb = z3 + ((size_t)(batch << 12)) * 128;
  f16x8 x3r[4];
#pragma unroll
  for (int pass = 0; pass < 4; ++pass) {
    const int pi = pass * 32 + (tid >> 4);
    const int p = bm0 + pi;
    const int* ip = idx + (size_t)p * K_;
    const int ir0 = ip[lid];
    const int ir1 = (lid < 4) ? ip[16 + lid] : 0;
    f16x8 mx = *reinterpret_cast<const f16x8*>(zb + (size_t)__shfl(ir0, 0, 16) * 128 + cb);
#pragma unroll
    for (int k = 1; k < K_; ++k) {
      const int g = (k < 16) ? __shfl(ir0, k, 16) : __shfl(ir1, k - 16, 16);
      const f16x8 v = *reinterpret_cast<const f16x8*>(zb + (size_t)g * 128 + cb);
#pragma unroll
      for (int q = 0; q < 8; ++q) mx[q] = v[q] > mx[q] ? v[q] : mx[q];
    }
    const f16x8 vc = *reinterpret_cast<const f16x8*>(z3 + (size_t)p * 128 + cb);
    f16x8 vo;
#pragma unroll
    for (int q = 0; q < 8; ++q) {
      const float e = (float)mx[q] - (float)vc[q] + bt[q];
      vo[q] = (_Float16)fmaxf(e, NEG * e);
    }
    x3r[pass] = vo;
    *reinterpret_cast<f16x8*>(h512 + (size_t)p * 512 + 128 + cb) = vo;
  }
  {
    const int kk = (cb >> 3) & 3;
    const int ts = cb >> 5;
    const int rr = (tid >> 4) & 15;
#pragma unroll
    for (int pp = 0; pp < 4; ++pp) {
      const int grp = pp * 2 + (tid >> 8);
      *reinterpret_cast<f16x8*>(&lds[ts * SB + grp * 512 + ((kk << 4) | rr) * 8]) = x3r[pp];
    }
  }
  __syncthreads();

  f32x4 acc[4][4];
#pragma unroll
  for (int i = 0; i < 4; ++i)
#pragma unroll
    for (int j = 0; j < 4; ++j) acc[i][j] = (f32x4){0.f, 0.f, 0.f, 0.f};
  __builtin_amdgcn_s_setprio(1);
#pragma unroll
  for (int t = 0; t < 4; ++t) {
    f16x8 av[4], wv[4];
#pragma unroll
    for (int i = 0; i < 4; ++i)
      av[i] = *reinterpret_cast<const f16x8*>(&lds[t * SB + (wr * 4 + i) * 512 + lane * 8]);
#pragma unroll
    for (int j = 0; j < 4; ++j)
      wv[j] = *reinterpret_cast<const f16x8*>(&lds[t * SB + (8 + wc * 4 + j) * 512 + lane * 8]);
#pragma unroll
    for (int i = 0; i < 4; ++i)
#pragma unroll
      for (int j = 0; j < 4; ++j)
        acc[i][j] = __builtin_amdgcn_mfma_f32_16x16x32_f16(av[i], wv[j], acc[i][j], 0, 0, 0);
  }
  __builtin_amdgcn_s_setprio(0);

#pragma unroll
  for (int j = 0; j < 4; ++j) {
    const int o = wc * 64 + 16 * j + lr;
#pragma unroll
    for (int i = 0; i < 4; ++i) {
      const int r0 = bm0 + wr * 64 + 16 * i + lk * 4;
#pragma unroll
      for (int q = 0; q < 4; ++q)
        z4out[(size_t)(r0 + q) * 256 + o] = (_Float16)acc[i][j][q];
    }
  }
}

// ---------------- edge max, standalone (O=256) -------------------------------
template <int O>
__global__ __launch_bounds__(256) void edge_max8(
    const _Float16* __restrict__ z, const int* __restrict__ idx,
    const float* __restrict__ betap, _Float16* __restrict__ out, int ldout) {
  constexpr int TPP = O / 8;
  constexpr int PPB = 256 / TPP;
  constexpr int NW = (K_ + TPP - 1) / TPP;
  const int t = threadIdx.x;
  const int batch = blockIdx.x & 7;
  const int chunk = blockIdx.x >> 3;
  const int p = (batch << 12) + chunk * PPB + t / TPP;
  const int lid = t % TPP;
  const int cb = lid * 8;
  const int* ip = idx + (size_t)p * K_;
  int ir[NW];
#pragma unroll
  for (int wv = 0; wv < NW; ++wv) {
    const int l = wv * TPP + lid;
    ir[wv] = (l < K_) ? ip[l] : ip[0];
  }
  const _Float16* zb = z + ((size_t)(batch << 12)) * O;

  f16x8 mx = *reinterpret_cast<const f16x8*>(zb + (size_t)__shfl(ir[0], 0, TPP) * O + cb);
#pragma unroll
  for (int k = 1; k < K_; ++k) {
    const int g = __shfl(ir[k / TPP], k % TPP, TPP);
    const f16x8 v = *reinterpret_cast<const f16x8*>(zb + (size_t)g * O + cb);
#pragma unroll
    for (int q = 0; q < 8; ++q) mx[q] = v[q] > mx[q] ? v[q] : mx[q];
  }
  const f16x8 vc = *reinterpret_cast<const f16x8*>(z + (size_t)p * O + cb);
  f16x8 vo;
#pragma unroll
  for (int q = 0; q < 8; ++q) {
    const float e = (float)mx[q] - (float)vc[q] + betap[cb + q];
    vo[q] = (_Float16)fmaxf(e, NEG * e);
  }
  *reinterpret_cast<f16x8*>(out + (size_t)p * ldout + cb) = vo;
}

// ---------------- L5+L6+L7 fused, 8-wave; 3-deep prefetch + setprio ----------
__global__ __launch_bounds__(512, 1) void gemm_l567(
    const _Float16* __restrict__ A,           // h512, ld 512
    const _Float16* __restrict__ W5,          // (256,512)
    const float* __restrict__ bt5,
    const _Float16* __restrict__ W6,          // (128,256)
    const float* __restrict__ bt6,
    const float* __restrict__ w7,             // (128)
    float* __restrict__ dout) {               // (M)
  constexpr int SB = 24 * 512;
  constexpr int H5 = 4 * SB;
  __shared__ _Float16 lds[4 * SB + 32768];    // 160KB

  const int tid = threadIdx.x, lane = tid & 63, wid = tid >> 6;
  const int wr = wid >> 2, wc = wid & 3;
  const int bid = blockIdx.x;
  const int bm0 = ((bid & 7) << 12) + (bid >> 3) * 128;  // batch-XCD swizzle
  const int lr = lane & 15, lk = lane >> 4;

  const _Float16* Abase = A + (size_t)(bm0 + lr) * 512 + lk * 8;
  const _Float16* W5b = W5 + (size_t)lr * 512 + lk * 8;

  f32x4 acc[4][4];
#pragma unroll
  for (int i = 0; i < 4; ++i)
#pragma unroll
    for (int j = 0; j < 4; ++j) acc[i][j] = (f32x4){0.f, 0.f, 0.f, 0.f};

  auto stage = [&](int buf, int k0) {
    _Float16* dst = &lds[buf * SB];
#pragma unroll
    for (int q = 0; q < 3; ++q) {
      const int g = wid * 3 + q;
      const _Float16* src = (g < 8)
          ? Abase + (size_t)16 * g * 512 + k0
          : W5b + (size_t)16 * (g - 8) * 512 + k0;
      gload_lds16(src, dst + g * 512);
    }
  };

  stage(0, 0);
  stage(1, 32);
  stage(2, 64);
#pragma unroll
  for (int t = 0; t < 16; ++t) {
    if (t + 3 < 16)       VMCNT(6);   // t+1,t+2 in flight
    else if (t + 2 < 16)  VMCNT(6);
    else if (t + 1 < 16)  VMCNT(3);
    else                  VMCNT(0);
    __builtin_amdgcn_s_barrier();
    if (t + 3 < 16) stage((t + 3) & 3, (t + 3) * 32);  // buf (t-1)&3, freed by barrier
    const _Float16* Ab = &lds[(t & 3) * SB];
    f16x8 av[4], wv[4];
#pragma unroll
    for (int i = 0; i < 4; ++i)
      av[i] = *reinterpret_cast<const f16x8*>(Ab + (wr * 4 + i) * 512 + lane * 8);
#pragma unroll
    for (int j = 0; j < 4; ++j)
      wv[j] = *reinterpret_cast<const f16x8*>(Ab + (8 + wc * 4 + j) * 512 + lane * 8);
    __builtin_amdgcn_s_setprio(1);
#pragma unroll
    for (int i = 0; i < 4; ++i)
#pragma unroll
      for (int j = 0; j < 4; ++j)
        acc[i][j] = __builtin_amdgcn_mfma_f32_16x16x32_f16(av[i], wv[j], acc[i][j], 0, 0, 0);
    __builtin_amdgcn_s_setprio(0);
  }

  // ---- epilogue: stage W6 into free ring [0..32768), scatter h5 into [H5..)
  {
    const _Float16* W6b = W6 + (size_t)lr * 256 + lk * 8;
#pragma unroll
    for (int q = 0; q < 8; ++q) {
      const int gg = wid * 8 + q;
      const int ob = gg >> 3, kk = gg & 7;
      gload_lds16(W6b + (size_t)16 * ob * 256 + kk * 32, &lds[gg * 512]);
    }
  }
#pragma unroll
  for (int j = 0; j < 4; ++j) {
    const int o = wc * 64 + 16 * j + lr;
    const float b5 = bt5[o];
    const int gcol = o >> 5;
    const int slotc = (o >> 3) & 3;
    const int elem = o & 7;
#pragma unroll
    for (int i = 0; i < 4; ++i) {
      const int rg = wr * 4 + i;
#pragma unroll
      for (int q = 0; q < 4; ++q) {
        const int rl = lk * 4 + q;
        float t = acc[i][j][q] + b5;
        t = fmaxf(t, NEG * t);
        lds[H5 + (rg * 8 + gcol) * 512 + (slotc * 16 + rl) * 8 + elem] = (_Float16)t;
      }
    }
  }
  __syncthreads();

  // ---- L6: 128x128, C=256; A from h5 LDS, W from W6 LDS
  f32x4 acc2[4][2];
#pragma unroll
  for (int i = 0; i < 4; ++i)
#pragma unroll
    for (int j = 0; j < 2; ++j) acc2[i][j] = (f32x4){0.f, 0.f, 0.f, 0.f};
  __builtin_amdgcn_s_setprio(1);
#pragma unroll
  for (int t = 0; t < 8; ++t) {
    f16x8 av[4], wv[2];
#pragma unroll
    for (int i = 0; i < 4; ++i)
      av[i] = *reinterpret_cast<const f16x8*>(&lds[H5 + ((wr * 4 + i) * 8 + t) * 512 + lane * 8]);
#pragma unroll
    for (int j = 0; j < 2; ++j)
      wv[j] = *reinterpret_cast<const f16x8*>(&lds[((wc * 2 + j) * 8 + t) * 512 + lane * 8]);
#pragma unroll
    for (int i = 0; i < 4; ++i)
#pragma unroll
      for (int j = 0; j < 2; ++j)
        acc2[i][j] = __builtin_amdgcn_mfma_f32_16x16x32_f16(av[i], wv[j], acc2[i][j], 0, 0, 0);
  }
  __builtin_amdgcn_s_setprio(0);

  // ---- L7: fused 128->1 dot + lrelu
  float* dotbuf = (float*)&lds[32768];
  float rowdot[4][4];
#pragma unroll
  for (int i = 0; i < 4; ++i)
#pragma unroll
    for (int q = 0; q < 4; ++q) rowdot[i][q] = 0.f;
#pragma unroll
  for (int j = 0; j < 2; ++j) {
    const int o = wc * 32 + 16 * j + lr;
    const float bt = bt6[o];
    const float wf = w7[o];
#pragma unroll
    for (int i = 0; i < 4; ++i)
#pragma unroll
      for (int q = 0; q < 4; ++q) {
        float t = acc2[i][j][q] + bt;
        t = fmaxf(t, NEG * t);
        rowdot[i][q] += t * wf;
      }
  }
#pragma unroll
  for (int i = 0; i < 4; ++i)
#pragma unroll
    for (int q = 0; q < 4; ++q) {
#pragma unroll
      for (int off = 1; off < 16; off <<= 1)
        rowdot[i][q] += __shfl_xor(rowdot[i][q], off, 16);
      if (lr == 0)
        dotbuf[(wr * 64 + 16 * i + lk * 4 + q) * 4 + wc] = rowdot[i][q];
    }
  __syncthreads();
  if (tid < 128) {
    const float s = dotbuf[tid * 4 + 0] + dotbuf[tid * 4 + 1] +
                    dotbuf[tid * 4 + 2] + dotbuf[tid * 4 + 3];
    dout[bm0 + tid] = fmaxf(s, NEG * s);
  }
}

// ---------------- launch -----------------------------------------------------
extern "C" void kernel_launch(void* const* d_in, const int* in_sizes, int n_in,
                              void* d_out, int out_size, void* d_ws, size_t ws_size,
                              hipStream_t stream) {
  const float* x  = (const float*)d_in[0];
  const int* idx  = (const int*)d_in[1];
  const float* w[7];
  for (int i = 0; i < 7; ++i) w[i] = (const float*)d_in[2 + i];
  const float* bn[24];
  for (int i = 0; i < 24; ++i) bn[i] = (const float*)d_in[9 + i];

  // ws: P@0 (32KB) | Wh@32KB (~0.42MB) | z_a@1MB (16MB) | h512@17MB (32MB) | z_b@49MB (16MB)
  float* P       = (float*)d_ws;
  _Float16* Wh   = (_Float16*)((char*)d_ws + (32 << 10));
  _Float16* z_a  = (_Float16*)((char*)d_ws + (1u << 20));
  _Float16* h512 = (_Float16*)((char*)d_ws + (17u << 20));
  _Float16* z_b  = (_Float16*)((char*)d_ws + (49u << 20));

  prep_c3<<<1329, 256, 0, stream>>>(
      x, w[0], w[1], w[2], w[3], w[4], w[5],
      bn[0], bn[1], bn[2], bn[3],   bn[4], bn[5], bn[6], bn[7],
      bn[8], bn[9], bn[10], bn[11], bn[12], bn[13], bn[14], bn[15],
      bn[16], bn[17], bn[18], bn[19], bn[20], bn[21], bn[22], bn[23],
      P, Wh, z_a);

  const float* bt1 = P + 64;
  const float* bt2 = P + 192;
  const float* bt3 = P + 384;
  const float* bt4 = P + 768;
  const float* bt5 = P + 1280;
  const float* bt6 = P + 1664;
  const _Float16* W2 = Wh + 0, *W3 = Wh + 4096, *W4 = Wh + 12288,
               *W5 = Wh + 45056, *W6 = Wh + 176128;

  // L1 edge + L2 GEMM fused (8-wave): z1 -> (x1 -> h512+0, z2 -> z_b ld 64)
  edge_gemm64<64><<<M_ / 128, 512, 0, stream>>>(z_a, idx, bt1, W2, h512 + 0, z_b, 64);
  // L2 edge + L3 GEMM fused (8-wave): z2 -> (x2 -> h512+64, z3 -> z_a ld 128)
  edge_gemm64<128><<<M_ / 128, 512, 0, stream>>>(z_b, idx, bt2, W3, h512 + 64, z_a, 128);
  // L3 edge + L4 GEMM fused (8-wave): z3 -> (x3 -> h512+128, z4 -> z_b ld 256)
  edge_gemm_l4<<<M_ / 128, 512, 0, stream>>>(z_a, idx, bt3, W4, h512, z_b);
  // L4 edge: z4 -> x4 (h512+256)
  edge_max8<256><<<M_ / 8, 256, 0, stream>>>(z_b, idx, bt4, h512 + 256, 512);
  // L5+L6+L7 fused (8-wave, LDS handoff): h512 -> d_out
  gemm_l567<<<M_ / 128, 512, 0, stream>>>(
      h512, W5, bt5, W6, bt6, w[6], (float*)d_out);
}